// Round 17
// baseline (110.071 us; speedup 1.0000x reference)
//
#include <hip/hip_runtime.h>
#include <stdint.h>

#define BATCH 4
#define TDIM 256
#define NPIX 4096
#define START 63
#define PLEN 193          // TDIM - START
#define THRESH 0.9f
#define ROUNDS 2          // round1's output is read; round2 was verify-only

typedef unsigned long long u64;
typedef unsigned int uint32;
typedef float vfloat4 __attribute__((ext_vector_type(4)));

// Zero-only blocks: stream zeros THROUGH L2 (same path as the 7 TB/s driver
// fill; NT/L2-bypass measured slower when co-running with compute).
__device__ __forceinline__ void zero_slice_block(
    vfloat4* __restrict__ zb, int zn, int zbid, int nzb)
{
    const int stride = nzb * 256;
    const vfloat4 z = {0.f, 0.f, 0.f, 0.f};
    int i = zbid * 256 + threadIdx.x;
    for (; i + stride < zn; i += 2 * stride) {
        zb[i] = z;
        zb[i + stride] = z;
    }
    if (i < zn) zb[i] = z;
}

// ---------------------------------------------------------------------------
// Kernel 1: per-pixel MLP features + L2-normalize. 4-way t-split, LDS reduce.
// Blocks >= NC are dedicated zero-streamers.
// ---------------------------------------------------------------------------
__global__ __launch_bounds__(256) void feat_kernel(
    const float* __restrict__ spike, const float* __restrict__ w1,
    const float* __restrict__ b1, const float* __restrict__ w2,
    const float* __restrict__ b2, float* __restrict__ fn,
    int* __restrict__ flag, vfloat4* __restrict__ zb, int zn, int nc)
{
    if (blockIdx.x >= nc) {                        // zero-only block
        zero_slice_block(zb, zn, blockIdx.x - nc, gridDim.x - nc);
        return;
    }
    __shared__ float s_part[3][64][17];            // +1 pad: conflict-free
    const int tid = threadIdx.x;
    const int lpix = tid & 63;
    const int q = tid >> 6;                        // wave = t-quarter
    const int g = blockIdx.x * 64 + lpix;          // 0..16383
    const int b = g >> 12;
    const int n = g & (NPIX - 1);
    const int t0 = q * 48;
    const int cnt = (q == 3) ? 49 : 48;            // 48*3 + 49 = 193
    const float* sp = spike + ((size_t)(b * TDIM + START + t0)) * NPIX + n;
    const float4* w14 = (const float4*)w1 + (size_t)t0 * 4;

    float h[16];
#pragma unroll
    for (int k = 0; k < 16; ++k) h[k] = 0.f;

    int i = 0;
    for (; i + 8 <= cnt; i += 8) {
        float x[8];
#pragma unroll
        for (int u = 0; u < 8; ++u) x[u] = sp[(size_t)(i + u) * NPIX];
#pragma unroll
        for (int u = 0; u < 8; ++u) {
            const float4 wa = w14[(i + u) * 4 + 0];   // uniform -> s_load
            const float4 wb = w14[(i + u) * 4 + 1];
            const float4 wc = w14[(i + u) * 4 + 2];
            const float4 wd = w14[(i + u) * 4 + 3];
            h[0] = fmaf(x[u], wa.x, h[0]);  h[1] = fmaf(x[u], wa.y, h[1]);
            h[2] = fmaf(x[u], wa.z, h[2]);  h[3] = fmaf(x[u], wa.w, h[3]);
            h[4] = fmaf(x[u], wb.x, h[4]);  h[5] = fmaf(x[u], wb.y, h[5]);
            h[6] = fmaf(x[u], wb.z, h[6]);  h[7] = fmaf(x[u], wb.w, h[7]);
            h[8] = fmaf(x[u], wc.x, h[8]);  h[9] = fmaf(x[u], wc.y, h[9]);
            h[10] = fmaf(x[u], wc.z, h[10]); h[11] = fmaf(x[u], wc.w, h[11]);
            h[12] = fmaf(x[u], wd.x, h[12]); h[13] = fmaf(x[u], wd.y, h[13]);
            h[14] = fmaf(x[u], wd.z, h[14]); h[15] = fmaf(x[u], wd.w, h[15]);
        }
    }
    for (; i < cnt; ++i) {
        float x = sp[(size_t)i * NPIX];
        const float4 wa = w14[i * 4 + 0];
        const float4 wb = w14[i * 4 + 1];
        const float4 wc = w14[i * 4 + 2];
        const float4 wd = w14[i * 4 + 3];
        h[0] = fmaf(x, wa.x, h[0]);  h[1] = fmaf(x, wa.y, h[1]);
        h[2] = fmaf(x, wa.z, h[2]);  h[3] = fmaf(x, wa.w, h[3]);
        h[4] = fmaf(x, wb.x, h[4]);  h[5] = fmaf(x, wb.y, h[5]);
        h[6] = fmaf(x, wb.z, h[6]);  h[7] = fmaf(x, wb.w, h[7]);
        h[8] = fmaf(x, wc.x, h[8]);  h[9] = fmaf(x, wc.y, h[9]);
        h[10] = fmaf(x, wc.z, h[10]); h[11] = fmaf(x, wc.w, h[11]);
        h[12] = fmaf(x, wd.x, h[12]); h[13] = fmaf(x, wd.y, h[13]);
        h[14] = fmaf(x, wd.z, h[14]); h[15] = fmaf(x, wd.w, h[15]);
    }

    if (q) {
#pragma unroll
        for (int k = 0; k < 16; ++k) s_part[q - 1][lpix][k] = h[k];
    }
    __syncthreads();
    if (q == 0) {
#pragma unroll
        for (int k = 0; k < 16; ++k)
            h[k] += s_part[0][lpix][k] + s_part[1][lpix][k] + s_part[2][lpix][k];
#pragma unroll
        for (int k = 0; k < 16; ++k) {
            float z = h[k] + b1[k];
            h[k] = z / (1.f + expf(-z));           // silu
        }
        float f[8];
#pragma unroll
        for (int m = 0; m < 8; ++m) f[m] = b2[m];
#pragma unroll
        for (int k = 0; k < 16; ++k) {
#pragma unroll
            for (int m = 0; m < 8; ++m)
                f[m] = fmaf(h[k], w2[k * 8 + m], f[m]);
        }
#pragma unroll
        for (int m = 0; m < 8; ++m) f[m] = f[m] / (1.f + expf(-f[m]));  // silu
        float nrm = 0.f;
#pragma unroll
        for (int m = 0; m < 8; ++m) nrm = fmaf(f[m], f[m], nrm);
        nrm = fmaxf(sqrtf(nrm), 1e-6f);
#pragma unroll
        for (int m = 0; m < 8; ++m) f[m] = f[m] / nrm;

        float4* o4 = (float4*)(fn + (size_t)g * 8);
        o4[0] = make_float4(f[0], f[1], f[2], f[3]);
        o4[1] = make_float4(f[4], f[5], f[6], f[7]);
    }
    if (blockIdx.x == 0 && tid == 0) *flag = 0;    // convergence flag
}

// ---------------------------------------------------------------------------
// Kernel 2: adjacency bitmask + lab1 = M(identity) = min set-bit per row.
// Dot-product summation kept STRICTLY sequential e0..e7 (matches XLA).
// Blocks >= NC are zero-streamers.
// ---------------------------------------------------------------------------
__global__ __launch_bounds__(256) void adj_kernel(
    const float* __restrict__ fn, u64* __restrict__ adj, int* __restrict__ lab,
    vfloat4* __restrict__ zb, int zn, int nc)
{
    if (blockIdx.x >= nc) {                        // zero-only block
        zero_slice_block(zb, zn, blockIdx.x - nc, gridDim.x - nc);
        return;
    }
    __shared__ float s_fj[1024 * 8];               // 32 KiB
    const int b  = blockIdx.x >> 8;
    const int i0 = (blockIdx.x & 255) << 4;
    const int tid = threadIdx.x;
    const int wave = tid >> 6, lane = tid & 63;
    const float* fnb = fn + (size_t)b * NPIX * 8;

    float fi[4][8];                                // 4 rows per wave
#pragma unroll
    for (int r = 0; r < 4; ++r) {
        const float* src = fnb + (size_t)(i0 + wave * 4 + r) * 8;
#pragma unroll
        for (int e = 0; e < 8; ++e) fi[r][e] = src[e];
    }
    u64 saved[4] = {0, 0, 0, 0};                   // word 'lane' of each row

    for (int jc = 0; jc < 4; ++jc) {
        __syncthreads();
        const float4* src4 = (const float4*)(fnb + (size_t)jc * 1024 * 8);
        float4* dst4 = (float4*)s_fj;
#pragma unroll
        for (int p = 0; p < 8; ++p) dst4[p * 256 + tid] = src4[p * 256 + tid];
        __syncthreads();

        for (int ww = 0; ww < 16; ++ww) {
            const int jl = ww * 64 + lane;
            const float4* pj = (const float4*)(s_fj + jl * 8);
            float4 a = pj[0], c = pj[1];
            float fj[8] = {a.x, a.y, a.z, a.w, c.x, c.y, c.z, c.w};
            const int widx = jc * 16 + ww;
#pragma unroll
            for (int r = 0; r < 4; ++r) {
                float d = 0.f;
#pragma unroll
                for (int e = 0; e < 8; ++e) d = fmaf(fj[e], fi[r][e], d);
                u64 mask = __ballot(d >= THRESH);
                if (lane == widx) saved[r] = mask;
            }
        }
    }
    u64* adjbase = adj + ((size_t)b * NPIX + i0) * 64;
#pragma unroll
    for (int r = 0; r < 4; ++r) {
        adjbase[(size_t)(wave * 4 + r) * 64 + lane] = saved[r];
        // lab1[row] = min set bit index (diag guarantees nonempty)
        int cand = saved[r] ? (lane * 64 + __ffsll(saved[r]) - 1) : NPIX;
#pragma unroll
        for (int off = 32; off > 0; off >>= 1)
            cand = min(cand, __shfl_xor(cand, off));
        if (lane == 0) lab[(b << 12) + i0 + wave * 4 + r] = cand;
    }
}

// ---------------------------------------------------------------------------
// Kernel 3: one round = J^3 then masked min, jmp rotate-swizzled in LDS
// (conflict-free both sides). Blocks >= NC are zero-streamers (they zero
// regardless of the convergence flag; compute blocks early-exit as before).
// ---------------------------------------------------------------------------
__global__ __launch_bounds__(256) void min_kernel(
    const u64* __restrict__ adj, const int* __restrict__ src,
    int* __restrict__ dst, int* __restrict__ flag, int round,
    vfloat4* __restrict__ zb, int zn, int nc)
{
    if (blockIdx.x >= nc) {                        // zero-only block
        zero_slice_block(zb, zn, blockIdx.x - nc, gridDim.x - nc);
        return;
    }
    if (round > 0 && flag[0] < round) return;      // converged: labels final
    __shared__ int sA[NPIX];                       // 16 KiB
    __shared__ int sB[NPIX];                       // 16 KiB (J^2 / swizzled jmp)
    __shared__ int s_chg;
    const int tid = threadIdx.x;
    if (tid == 0) s_chg = 0;
    const int wave = tid >> 6, lane = tid & 63;
    const int row0 = blockIdx.x * 32 + wave * 8;   // 8 rows per wave
    const int base = (row0 >> 12) << 12;           // batch base

    const int4* g4 = (const int4*)(src + base);
    int4* s4 = (int4*)sA;
#pragma unroll
    for (int p = 0; p < 4; ++p) s4[p * 256 + tid] = g4[p * 256 + tid];
    __syncthreads();
    // J^1: sA -> sB ; J^2: sB -> sA (linear layouts)
#pragma unroll
    for (int p = 0; p < 16; ++p) {
        int j = p * 256 + tid;
        sB[j] = sA[min(sA[j], NPIX - 1)];
    }
    __syncthreads();
#pragma unroll
    for (int p = 0; p < 16; ++p) {
        int j = p * 256 + tid;
        sA[j] = sB[min(sB[j], NPIX - 1)];
    }
    __syncthreads();
    // J^3: sA -> sB, written in rotate-swizzled transposed layout
#pragma unroll
    for (int p = 0; p < 16; ++p) {
        int j = p * 256 + tid;
        int v = sA[min(sA[j], NPIX - 1)];
        int bj = j & 63;                           // = lane
        int lj = j >> 6;                           // uniform per (p,wave)
        sB[(bj << 6) + ((lj + bj) & 63)] = v;      // conflict-free write
    }
    __syncthreads();

    const u64* arow = adj + (size_t)row0 * 64;
    uint32 lo[8], hi[8];
#pragma unroll
    for (int q = 0; q < 8; ++q) {
        u64 w = arow[(size_t)q * 64 + lane];       // word 'lane' of row q
        lo[q] = (uint32)w; hi[q] = (uint32)(w >> 32);
    }

    int m[8];
#pragma unroll
    for (int q = 0; q < 8; ++q) m[q] = NPIX;       // reference uses N as +inf
#pragma unroll
    for (int b = 0; b < 32; ++b) {
        const int jv = sB[(b << 6) + ((lane + b) & 63)];
#pragma unroll
        for (int q = 0; q < 8; ++q)
            m[q] = min(m[q], (lo[q] & (1u << b)) ? jv : NPIX);
    }
#pragma unroll
    for (int b = 0; b < 32; ++b) {
        const int jv = sB[((b + 32) << 6) + ((lane + b + 32) & 63)];
#pragma unroll
        for (int q = 0; q < 8; ++q)
            m[q] = min(m[q], (hi[q] & (1u << b)) ? jv : NPIX);
    }
#pragma unroll
    for (int off = 32; off > 0; off >>= 1) {
#pragma unroll
        for (int q = 0; q < 8; ++q) m[q] = min(m[q], __shfl_xor(m[q], off));
    }

    if (lane == 0) {
        bool chg = false;
#pragma unroll
        for (int q = 0; q < 8; ++q) {
            dst[row0 + q] = m[q];
            chg |= (m[q] != src[row0 + q]);
        }
        if (chg) s_chg = 1;
    }
    __syncthreads();
    if (tid == 0 && s_chg) *flag = round + 1;      // plain store, same value
}

// ---------------------------------------------------------------------------
// Kernel 4 (fallback only): standalone zero of the whole output.
// ---------------------------------------------------------------------------
__global__ __launch_bounds__(256) void zero_kernel(vfloat4* __restrict__ out)
{
    size_t idx = (size_t)blockIdx.x * 256 + threadIdx.x;
    const size_t stride = (size_t)2048 * 256;
    const vfloat4 z = {0.f, 0.f, 0.f, 0.f};
#pragma unroll
    for (int k = 0; k < 32; ++k) {
        out[idx] = z;
        idx += stride;
    }
}

// ---------------------------------------------------------------------------
// Kernel 5: final jump + is_root + cumsum rank + SCATTER of ones into the
// zeroed output: out[b][rank[lab[i]]][i] = 1.0f. One block per batch.
// ---------------------------------------------------------------------------
__global__ __launch_bounds__(256) void comp_scatter_kernel(
    const int* __restrict__ labsrc, float* __restrict__ out)
{
    __shared__ int s_lab[NPIX];                    // 16 KiB
    __shared__ int s_rank[NPIX];                   // 16 KiB
    __shared__ int s_wsum[4];
    const int b = blockIdx.x, tid = threadIdx.x;
    const int* lb = labsrc + (b << 12);

    for (int i = tid; i < NPIX; i += 256) s_lab[i] = lb[i];
    __syncthreads();

    // final pointer-jump (identity at fixed point; kept for exactness)
    int regs[16];
#pragma unroll
    for (int k = 0; k < 16; ++k) {
        int i = k * 256 + tid;
        regs[k] = s_lab[min(s_lab[i], NPIX - 1)];
    }
    __syncthreads();
#pragma unroll
    for (int k = 0; k < 16; ++k) s_lab[k * 256 + tid] = regs[k];
    __syncthreads();

    // inclusive cumsum of is_root, 16 contiguous elems per thread
    int loc[16];
    int sum = 0;
#pragma unroll
    for (int k = 0; k < 16; ++k) {
        int i = tid * 16 + k;
        sum += (s_lab[i] == i) ? 1 : 0;
        loc[k] = sum;
    }
    const int lane = tid & 63, wave = tid >> 6;
    int v = sum;
    for (int off = 1; off < 64; off <<= 1) {
        int u = __shfl_up(v, off);
        if (lane >= off) v += u;
    }
    if (lane == 63) s_wsum[wave] = v;
    __syncthreads();
    int waveoff = 0;
    for (int ww = 0; ww < 4; ++ww)
        if (ww < wave) waveoff += s_wsum[ww];
    const int excl = waveoff + v - sum;
#pragma unroll
    for (int k = 0; k < 16; ++k) s_rank[tid * 16 + k] = excl + loc[k] - 1;
    __syncthreads();

    float* ob = out + ((size_t)b << 24);           // batch base (4096*4096)
#pragma unroll
    for (int k = 0; k < 16; ++k) {
        int i = k * 256 + tid;
        int r = s_rank[min(s_lab[i], NPIX - 1)];   // JAX clamp on rank[labels]
        ob[((size_t)r << 12) + i] = 1.0f;          // one-hot scatter
    }
}

// ---------------------------------------------------------------------------
extern "C" void kernel_launch(void* const* d_in, const int* in_sizes, int n_in,
                              void* d_out, int out_size, void* d_ws, size_t ws_size,
                              hipStream_t stream)
{
    const float* spike = (const float*)d_in[0];
    const float* w1 = (const float*)d_in[1];
    const float* b1 = (const float*)d_in[2];
    const float* w2 = (const float*)d_in[3];
    const float* b2 = (const float*)d_in[4];

    const size_t ADJ_B = (size_t)8 * 1024 * 1024;          // adj bitmask
    const size_t FN_B  = (size_t)BATCH * NPIX * 8 * 4;     // features, 512 KiB
    const size_t LAB_B = (size_t)BATCH * NPIX * 4;         // one label buf
    const bool use_ws = ws_size >= ADJ_B + FN_B + 2 * LAB_B + 64;

    u64*   adj;
    float* fn;
    int *labA, *labB, *flag;
    if (use_ws) {
        char* w = (char*)d_ws;
        adj  = (u64*)w;
        fn   = (float*)(w + ADJ_B);
        labA = (int*)(w + ADJ_B + FN_B);
        labB = labA + BATCH * NPIX;
        flag = labB + BATCH * NPIX;
    } else {                                        // fallback: R12 layout
        adj  = (u64*)d_out;
        fn   = (float*)((char*)d_out + ADJ_B);
        labA = (int*)d_ws;
        labB = labA + BATCH * NPIX;
        flag = labB + BATCH * NPIX;
    }

    vfloat4* out4 = (vfloat4*)d_out;
    const int MI = 1024 * 1024;
    // zero-slice plan (float4 units, total 16Mi = 268 MB), sized to each
    // kernel's idle-wave capacity:
    //   feat 5Mi (768 zero blks) | adj 3Mi (256) | round0 4Mi (512) | round1 4Mi (512)
    const int Z_FEAT = 5 * MI, Z_ADJ = 3 * MI, Z_R = 4 * MI;
    vfloat4* zf = use_ws ? out4 : nullptr;
    vfloat4* za = use_ws ? out4 + (size_t)Z_FEAT : nullptr;
    vfloat4* z0 = use_ws ? out4 + (size_t)(Z_FEAT + Z_ADJ) : nullptr;
    vfloat4* z1 = use_ws ? out4 + (size_t)(Z_FEAT + Z_ADJ + Z_R) : nullptr;
    const int ZB_FEAT = use_ws ? 768 : 0;
    const int ZB_ADJ  = use_ws ? 256 : 0;          // adj at 5-blk/CU LDS cap
    const int ZB_MIN  = use_ws ? 512 : 0;

    const int NC_FEAT = BATCH * NPIX / 64;         // 256
    const int NC_ADJ  = BATCH * 256;               // 1024
    const int NC_MIN  = BATCH * NPIX / 32;         // 512

    feat_kernel<<<NC_FEAT + ZB_FEAT, 256, 0, stream>>>(
        spike, w1, b1, w2, b2, fn, flag, zf, use_ws ? Z_FEAT : 0, NC_FEAT);
    adj_kernel<<<NC_ADJ + ZB_ADJ, 256, 0, stream>>>(
        fn, adj, labA, za, use_ws ? Z_ADJ : 0, NC_ADJ);

    int* bufs[2] = {labA, labB};
    vfloat4* zr[2] = {z0, z1};
    for (int r = 0; r < ROUNDS; ++r)
        min_kernel<<<NC_MIN + ZB_MIN, 256, 0, stream>>>(
            adj, bufs[r & 1], bufs[(r + 1) & 1], flag, r,
            zr[r], use_ws ? Z_R : 0, NC_MIN);

    if (!use_ws)
        zero_kernel<<<2048, 256, 0, stream>>>(out4);

    // final labels = round1's output (bufs[0])
    comp_scatter_kernel<<<BATCH, 256, 0, stream>>>(bufs[0], (float*)d_out);
}

// Round 18
// 98.779 us; speedup vs baseline: 1.1143x; 1.1143x over previous
//
#include <hip/hip_runtime.h>
#include <stdint.h>

#define BATCH 4
#define TDIM 256
#define NPIX 4096
#define START 63
#define PLEN 193          // TDIM - START
#define THRESH 0.9f
#define ROUNDS 2          // round1's output is read; round2 was verify-only

typedef unsigned long long u64;
typedef unsigned int uint32;
typedef float vfloat4 __attribute__((ext_vector_type(4)));

// Zero-only blocks: NONTEMPORAL stores (R16-proven: NT wins when co-running
// with compute; through-L2 stores regressed 14 us in R17 by thrashing the
// compute blocks' read lines).
__device__ __forceinline__ void zero_slice_block(
    vfloat4* __restrict__ zb, int zn, int zbid, int nzb)
{
    const int stride = nzb * 256;
    const vfloat4 z = {0.f, 0.f, 0.f, 0.f};
    int i = zbid * 256 + threadIdx.x;
    for (; i + stride < zn; i += 2 * stride) {
        __builtin_nontemporal_store(z, zb + i);
        __builtin_nontemporal_store(z, zb + i + stride);
    }
    if (i < zn) __builtin_nontemporal_store(z, zb + i);
}

// ---------------------------------------------------------------------------
// Kernel 1: per-pixel MLP features + L2-normalize. 4-way t-split, LDS reduce.
// Blocks >= NC are dedicated zero-streamers.
// ---------------------------------------------------------------------------
__global__ __launch_bounds__(256) void feat_kernel(
    const float* __restrict__ spike, const float* __restrict__ w1,
    const float* __restrict__ b1, const float* __restrict__ w2,
    const float* __restrict__ b2, float* __restrict__ fn,
    int* __restrict__ flag, vfloat4* __restrict__ zb, int zn, int nc)
{
    if (blockIdx.x >= nc) {                        // zero-only block
        zero_slice_block(zb, zn, blockIdx.x - nc, gridDim.x - nc);
        return;
    }
    __shared__ float s_part[3][64][17];            // +1 pad: conflict-free
    const int tid = threadIdx.x;
    const int lpix = tid & 63;
    const int q = tid >> 6;                        // wave = t-quarter
    const int g = blockIdx.x * 64 + lpix;          // 0..16383
    const int b = g >> 12;
    const int n = g & (NPIX - 1);
    const int t0 = q * 48;
    const int cnt = (q == 3) ? 49 : 48;            // 48*3 + 49 = 193
    const float* sp = spike + ((size_t)(b * TDIM + START + t0)) * NPIX + n;
    const float4* w14 = (const float4*)w1 + (size_t)t0 * 4;

    float h[16];
#pragma unroll
    for (int k = 0; k < 16; ++k) h[k] = 0.f;

    int i = 0;
    for (; i + 8 <= cnt; i += 8) {
        float x[8];
#pragma unroll
        for (int u = 0; u < 8; ++u) x[u] = sp[(size_t)(i + u) * NPIX];
#pragma unroll
        for (int u = 0; u < 8; ++u) {
            const float4 wa = w14[(i + u) * 4 + 0];   // uniform -> s_load
            const float4 wb = w14[(i + u) * 4 + 1];
            const float4 wc = w14[(i + u) * 4 + 2];
            const float4 wd = w14[(i + u) * 4 + 3];
            h[0] = fmaf(x[u], wa.x, h[0]);  h[1] = fmaf(x[u], wa.y, h[1]);
            h[2] = fmaf(x[u], wa.z, h[2]);  h[3] = fmaf(x[u], wa.w, h[3]);
            h[4] = fmaf(x[u], wb.x, h[4]);  h[5] = fmaf(x[u], wb.y, h[5]);
            h[6] = fmaf(x[u], wb.z, h[6]);  h[7] = fmaf(x[u], wb.w, h[7]);
            h[8] = fmaf(x[u], wc.x, h[8]);  h[9] = fmaf(x[u], wc.y, h[9]);
            h[10] = fmaf(x[u], wc.z, h[10]); h[11] = fmaf(x[u], wc.w, h[11]);
            h[12] = fmaf(x[u], wd.x, h[12]); h[13] = fmaf(x[u], wd.y, h[13]);
            h[14] = fmaf(x[u], wd.z, h[14]); h[15] = fmaf(x[u], wd.w, h[15]);
        }
    }
    for (; i < cnt; ++i) {
        float x = sp[(size_t)i * NPIX];
        const float4 wa = w14[i * 4 + 0];
        const float4 wb = w14[i * 4 + 1];
        const float4 wc = w14[i * 4 + 2];
        const float4 wd = w14[i * 4 + 3];
        h[0] = fmaf(x, wa.x, h[0]);  h[1] = fmaf(x, wa.y, h[1]);
        h[2] = fmaf(x, wa.z, h[2]);  h[3] = fmaf(x, wa.w, h[3]);
        h[4] = fmaf(x, wb.x, h[4]);  h[5] = fmaf(x, wb.y, h[5]);
        h[6] = fmaf(x, wb.z, h[6]);  h[7] = fmaf(x, wb.w, h[7]);
        h[8] = fmaf(x, wc.x, h[8]);  h[9] = fmaf(x, wc.y, h[9]);
        h[10] = fmaf(x, wc.z, h[10]); h[11] = fmaf(x, wc.w, h[11]);
        h[12] = fmaf(x, wd.x, h[12]); h[13] = fmaf(x, wd.y, h[13]);
        h[14] = fmaf(x, wd.z, h[14]); h[15] = fmaf(x, wd.w, h[15]);
    }

    if (q) {
#pragma unroll
        for (int k = 0; k < 16; ++k) s_part[q - 1][lpix][k] = h[k];
    }
    __syncthreads();
    if (q == 0) {
#pragma unroll
        for (int k = 0; k < 16; ++k)
            h[k] += s_part[0][lpix][k] + s_part[1][lpix][k] + s_part[2][lpix][k];
#pragma unroll
        for (int k = 0; k < 16; ++k) {
            float z = h[k] + b1[k];
            h[k] = z / (1.f + expf(-z));           // silu
        }
        float f[8];
#pragma unroll
        for (int m = 0; m < 8; ++m) f[m] = b2[m];
#pragma unroll
        for (int k = 0; k < 16; ++k) {
#pragma unroll
            for (int m = 0; m < 8; ++m)
                f[m] = fmaf(h[k], w2[k * 8 + m], f[m]);
        }
#pragma unroll
        for (int m = 0; m < 8; ++m) f[m] = f[m] / (1.f + expf(-f[m]));  // silu
        float nrm = 0.f;
#pragma unroll
        for (int m = 0; m < 8; ++m) nrm = fmaf(f[m], f[m], nrm);
        nrm = fmaxf(sqrtf(nrm), 1e-6f);
#pragma unroll
        for (int m = 0; m < 8; ++m) f[m] = f[m] / nrm;

        float4* o4 = (float4*)(fn + (size_t)g * 8);
        o4[0] = make_float4(f[0], f[1], f[2], f[3]);
        o4[1] = make_float4(f[4], f[5], f[6], f[7]);
    }
    if (blockIdx.x == 0 && tid == 0) *flag = 0;    // convergence flag
}

// ---------------------------------------------------------------------------
// Kernel 2: adjacency bitmask + lab1 = M(identity) = min set-bit per row.
// Dot-product summation kept STRICTLY sequential e0..e7 (matches XLA).
// Blocks >= NC are zero-streamers.
// ---------------------------------------------------------------------------
__global__ __launch_bounds__(256) void adj_kernel(
    const float* __restrict__ fn, u64* __restrict__ adj, int* __restrict__ lab,
    vfloat4* __restrict__ zb, int zn, int nc)
{
    if (blockIdx.x >= nc) {                        // zero-only block
        zero_slice_block(zb, zn, blockIdx.x - nc, gridDim.x - nc);
        return;
    }
    __shared__ float s_fj[1024 * 8];               // 32 KiB
    const int b  = blockIdx.x >> 8;
    const int i0 = (blockIdx.x & 255) << 4;
    const int tid = threadIdx.x;
    const int wave = tid >> 6, lane = tid & 63;
    const float* fnb = fn + (size_t)b * NPIX * 8;

    float fi[4][8];                                // 4 rows per wave
#pragma unroll
    for (int r = 0; r < 4; ++r) {
        const float* src = fnb + (size_t)(i0 + wave * 4 + r) * 8;
#pragma unroll
        for (int e = 0; e < 8; ++e) fi[r][e] = src[e];
    }
    u64 saved[4] = {0, 0, 0, 0};                   // word 'lane' of each row

    for (int jc = 0; jc < 4; ++jc) {
        __syncthreads();
        const float4* src4 = (const float4*)(fnb + (size_t)jc * 1024 * 8);
        float4* dst4 = (float4*)s_fj;
#pragma unroll
        for (int p = 0; p < 8; ++p) dst4[p * 256 + tid] = src4[p * 256 + tid];
        __syncthreads();

        for (int ww = 0; ww < 16; ++ww) {
            const int jl = ww * 64 + lane;
            const float4* pj = (const float4*)(s_fj + jl * 8);
            float4 a = pj[0], c = pj[1];
            float fj[8] = {a.x, a.y, a.z, a.w, c.x, c.y, c.z, c.w};
            const int widx = jc * 16 + ww;
#pragma unroll
            for (int r = 0; r < 4; ++r) {
                float d = 0.f;
#pragma unroll
                for (int e = 0; e < 8; ++e) d = fmaf(fj[e], fi[r][e], d);
                u64 mask = __ballot(d >= THRESH);
                if (lane == widx) saved[r] = mask;
            }
        }
    }
    u64* adjbase = adj + ((size_t)b * NPIX + i0) * 64;
#pragma unroll
    for (int r = 0; r < 4; ++r) {
        adjbase[(size_t)(wave * 4 + r) * 64 + lane] = saved[r];
        // lab1[row] = min set bit index (diag guarantees nonempty)
        int cand = saved[r] ? (lane * 64 + __ffsll(saved[r]) - 1) : NPIX;
#pragma unroll
        for (int off = 32; off > 0; off >>= 1)
            cand = min(cand, __shfl_xor(cand, off));
        if (lane == 0) lab[(b << 12) + i0 + wave * 4 + r] = cand;
    }
}

// ---------------------------------------------------------------------------
// Kernel 3: one round = J^3 then masked min, jmp rotate-swizzled in LDS
// (conflict-free both sides). Blocks >= NC are zero-streamers (they zero
// regardless of the convergence flag; compute blocks early-exit as before).
// ---------------------------------------------------------------------------
__global__ __launch_bounds__(256) void min_kernel(
    const u64* __restrict__ adj, const int* __restrict__ src,
    int* __restrict__ dst, int* __restrict__ flag, int round,
    vfloat4* __restrict__ zb, int zn, int nc)
{
    if (blockIdx.x >= nc) {                        // zero-only block
        zero_slice_block(zb, zn, blockIdx.x - nc, gridDim.x - nc);
        return;
    }
    if (round > 0 && flag[0] < round) return;      // converged: labels final
    __shared__ int sA[NPIX];                       // 16 KiB
    __shared__ int sB[NPIX];                       // 16 KiB (J^2 / swizzled jmp)
    __shared__ int s_chg;
    const int tid = threadIdx.x;
    if (tid == 0) s_chg = 0;
    const int wave = tid >> 6, lane = tid & 63;
    const int row0 = blockIdx.x * 32 + wave * 8;   // 8 rows per wave
    const int base = (row0 >> 12) << 12;           // batch base

    const int4* g4 = (const int4*)(src + base);
    int4* s4 = (int4*)sA;
#pragma unroll
    for (int p = 0; p < 4; ++p) s4[p * 256 + tid] = g4[p * 256 + tid];
    __syncthreads();
    // J^1: sA -> sB ; J^2: sB -> sA (linear layouts)
#pragma unroll
    for (int p = 0; p < 16; ++p) {
        int j = p * 256 + tid;
        sB[j] = sA[min(sA[j], NPIX - 1)];
    }
    __syncthreads();
#pragma unroll
    for (int p = 0; p < 16; ++p) {
        int j = p * 256 + tid;
        sA[j] = sB[min(sB[j], NPIX - 1)];
    }
    __syncthreads();
    // J^3: sA -> sB, written in rotate-swizzled transposed layout
#pragma unroll
    for (int p = 0; p < 16; ++p) {
        int j = p * 256 + tid;
        int v = sA[min(sA[j], NPIX - 1)];
        int bj = j & 63;                           // = lane
        int lj = j >> 6;                           // uniform per (p,wave)
        sB[(bj << 6) + ((lj + bj) & 63)] = v;      // conflict-free write
    }
    __syncthreads();

    const u64* arow = adj + (size_t)row0 * 64;
    uint32 lo[8], hi[8];
#pragma unroll
    for (int q = 0; q < 8; ++q) {
        u64 w = arow[(size_t)q * 64 + lane];       // word 'lane' of row q
        lo[q] = (uint32)w; hi[q] = (uint32)(w >> 32);
    }

    int m[8];
#pragma unroll
    for (int q = 0; q < 8; ++q) m[q] = NPIX;       // reference uses N as +inf
#pragma unroll
    for (int b = 0; b < 32; ++b) {
        const int jv = sB[(b << 6) + ((lane + b) & 63)];
#pragma unroll
        for (int q = 0; q < 8; ++q)
            m[q] = min(m[q], (lo[q] & (1u << b)) ? jv : NPIX);
    }
#pragma unroll
    for (int b = 0; b < 32; ++b) {
        const int jv = sB[((b + 32) << 6) + ((lane + b + 32) & 63)];
#pragma unroll
        for (int q = 0; q < 8; ++q)
            m[q] = min(m[q], (hi[q] & (1u << b)) ? jv : NPIX);
    }
#pragma unroll
    for (int off = 32; off > 0; off >>= 1) {
#pragma unroll
        for (int q = 0; q < 8; ++q) m[q] = min(m[q], __shfl_xor(m[q], off));
    }

    if (lane == 0) {
        bool chg = false;
#pragma unroll
        for (int q = 0; q < 8; ++q) {
            dst[row0 + q] = m[q];
            chg |= (m[q] != src[row0 + q]);
        }
        if (chg) s_chg = 1;
    }
    __syncthreads();
    if (tid == 0 && s_chg) *flag = round + 1;      // plain store, same value
}

// ---------------------------------------------------------------------------
// Kernel 4 (fallback only): standalone zero of the whole output.
// ---------------------------------------------------------------------------
__global__ __launch_bounds__(256) void zero_kernel(vfloat4* __restrict__ out)
{
    size_t idx = (size_t)blockIdx.x * 256 + threadIdx.x;
    const size_t stride = (size_t)2048 * 256;
    const vfloat4 z = {0.f, 0.f, 0.f, 0.f};
#pragma unroll
    for (int k = 0; k < 32; ++k) {
        out[idx] = z;
        idx += stride;
    }
}

// ---------------------------------------------------------------------------
// Kernel 5: final jump + is_root + cumsum rank + SCATTER of ones into the
// zeroed output: out[b][rank[lab[i]]][i] = 1.0f. One block per batch.
// ---------------------------------------------------------------------------
__global__ __launch_bounds__(256) void comp_scatter_kernel(
    const int* __restrict__ labsrc, float* __restrict__ out)
{
    __shared__ int s_lab[NPIX];                    // 16 KiB
    __shared__ int s_rank[NPIX];                   // 16 KiB
    __shared__ int s_wsum[4];
    const int b = blockIdx.x, tid = threadIdx.x;
    const int* lb = labsrc + (b << 12);

    for (int i = tid; i < NPIX; i += 256) s_lab[i] = lb[i];
    __syncthreads();

    // final pointer-jump (identity at fixed point; kept for exactness)
    int regs[16];
#pragma unroll
    for (int k = 0; k < 16; ++k) {
        int i = k * 256 + tid;
        regs[k] = s_lab[min(s_lab[i], NPIX - 1)];
    }
    __syncthreads();
#pragma unroll
    for (int k = 0; k < 16; ++k) s_lab[k * 256 + tid] = regs[k];
    __syncthreads();

    // inclusive cumsum of is_root, 16 contiguous elems per thread
    int loc[16];
    int sum = 0;
#pragma unroll
    for (int k = 0; k < 16; ++k) {
        int i = tid * 16 + k;
        sum += (s_lab[i] == i) ? 1 : 0;
        loc[k] = sum;
    }
    const int lane = tid & 63, wave = tid >> 6;
    int v = sum;
    for (int off = 1; off < 64; off <<= 1) {
        int u = __shfl_up(v, off);
        if (lane >= off) v += u;
    }
    if (lane == 63) s_wsum[wave] = v;
    __syncthreads();
    int waveoff = 0;
    for (int ww = 0; ww < 4; ++ww)
        if (ww < wave) waveoff += s_wsum[ww];
    const int excl = waveoff + v - sum;
#pragma unroll
    for (int k = 0; k < 16; ++k) s_rank[tid * 16 + k] = excl + loc[k] - 1;
    __syncthreads();

    float* ob = out + ((size_t)b << 24);           // batch base (4096*4096)
#pragma unroll
    for (int k = 0; k < 16; ++k) {
        int i = k * 256 + tid;
        int r = s_rank[min(s_lab[i], NPIX - 1)];   // JAX clamp on rank[labels]
        ob[((size_t)r << 12) + i] = 1.0f;          // one-hot scatter
    }
}

// ---------------------------------------------------------------------------
extern "C" void kernel_launch(void* const* d_in, const int* in_sizes, int n_in,
                              void* d_out, int out_size, void* d_ws, size_t ws_size,
                              hipStream_t stream)
{
    const float* spike = (const float*)d_in[0];
    const float* w1 = (const float*)d_in[1];
    const float* b1 = (const float*)d_in[2];
    const float* w2 = (const float*)d_in[3];
    const float* b2 = (const float*)d_in[4];

    const size_t ADJ_B = (size_t)8 * 1024 * 1024;          // adj bitmask
    const size_t FN_B  = (size_t)BATCH * NPIX * 8 * 4;     // features, 512 KiB
    const size_t LAB_B = (size_t)BATCH * NPIX * 4;         // one label buf
    const bool use_ws = ws_size >= ADJ_B + FN_B + 2 * LAB_B + 64;

    u64*   adj;
    float* fn;
    int *labA, *labB, *flag;
    if (use_ws) {
        char* w = (char*)d_ws;
        adj  = (u64*)w;
        fn   = (float*)(w + ADJ_B);
        labA = (int*)(w + ADJ_B + FN_B);
        labB = labA + BATCH * NPIX;
        flag = labB + BATCH * NPIX;
    } else {                                        // fallback: R12 layout
        adj  = (u64*)d_out;
        fn   = (float*)((char*)d_out + ADJ_B);
        labA = (int*)d_ws;
        labB = labA + BATCH * NPIX;
        flag = labB + BATCH * NPIX;
    }

    vfloat4* out4 = (vfloat4*)d_out;
    const int MI = 1024 * 1024;
    // zero-slice plan (float4 units, total 16Mi = 268 MB), NT stores,
    // sized to each kernel's idle-wave capacity:
    //   feat 5Mi (768 zero blks) | adj 3Mi (256) | round0 4Mi (512) | round1 4Mi (512)
    const int Z_FEAT = 5 * MI, Z_ADJ = 3 * MI, Z_R = 4 * MI;
    vfloat4* zf = use_ws ? out4 : nullptr;
    vfloat4* za = use_ws ? out4 + (size_t)Z_FEAT : nullptr;
    vfloat4* z0 = use_ws ? out4 + (size_t)(Z_FEAT + Z_ADJ) : nullptr;
    vfloat4* z1 = use_ws ? out4 + (size_t)(Z_FEAT + Z_ADJ + Z_R) : nullptr;
    const int ZB_FEAT = use_ws ? 768 : 0;
    const int ZB_ADJ  = use_ws ? 256 : 0;          // adj at 5-blk/CU LDS cap
    const int ZB_MIN  = use_ws ? 512 : 0;

    const int NC_FEAT = BATCH * NPIX / 64;         // 256
    const int NC_ADJ  = BATCH * 256;               // 1024
    const int NC_MIN  = BATCH * NPIX / 32;         // 512

    feat_kernel<<<NC_FEAT + ZB_FEAT, 256, 0, stream>>>(
        spike, w1, b1, w2, b2, fn, flag, zf, use_ws ? Z_FEAT : 0, NC_FEAT);
    adj_kernel<<<NC_ADJ + ZB_ADJ, 256, 0, stream>>>(
        fn, adj, labA, za, use_ws ? Z_ADJ : 0, NC_ADJ);

    int* bufs[2] = {labA, labB};
    vfloat4* zr[2] = {z0, z1};
    for (int r = 0; r < ROUNDS; ++r)
        min_kernel<<<NC_MIN + ZB_MIN, 256, 0, stream>>>(
            adj, bufs[r & 1], bufs[(r + 1) & 1], flag, r,
            zr[r], use_ws ? Z_R : 0, NC_MIN);

    if (!use_ws)
        zero_kernel<<<2048, 256, 0, stream>>>(out4);

    // final labels = round1's output (bufs[0])
    comp_scatter_kernel<<<BATCH, 256, 0, stream>>>(bufs[0], (float*)d_out);
}

// Round 19
// 96.528 us; speedup vs baseline: 1.1403x; 1.0233x over previous
//
#include <hip/hip_runtime.h>
#include <stdint.h>

#define BATCH 4
#define TDIM 256
#define NPIX 4096
#define START 63
#define PLEN 193          // TDIM - START
#define THRESH 0.9f
#define ROUNDS 2          // round1's output is read; round2 was verify-only

typedef unsigned long long u64;
typedef unsigned int uint32;
typedef float vfloat4 __attribute__((ext_vector_type(4)));

// Zero-only blocks: stream nontemporal zeros. Runs CONCURRENTLY with the
// compute blocks of the same kernel (co-resident waves, different pipes).
// NT is required: through-L2 zero stores thrash compute reads (R17: -14us).
__device__ __forceinline__ void zero_slice_block(
    vfloat4* __restrict__ zb, int zn, int zbid, int nzb)
{
    const int stride = nzb * 256;
    const vfloat4 z = {0.f, 0.f, 0.f, 0.f};
    for (int i = zbid * 256 + threadIdx.x; i < zn; i += stride)
        __builtin_nontemporal_store(z, zb + i);
}

// ---------------------------------------------------------------------------
// Kernel 1: per-pixel MLP features + L2-normalize. 4-way t-split, LDS reduce.
// Blocks >= NC are dedicated zero-streamers (64 MB slice).
// ---------------------------------------------------------------------------
__global__ __launch_bounds__(256) void feat_kernel(
    const float* __restrict__ spike, const float* __restrict__ w1,
    const float* __restrict__ b1, const float* __restrict__ w2,
    const float* __restrict__ b2, float* __restrict__ fn,
    int* __restrict__ flag, vfloat4* __restrict__ zb, int zn, int nc)
{
    if (blockIdx.x >= nc) {                        // zero-only block
        zero_slice_block(zb, zn, blockIdx.x - nc, gridDim.x - nc);
        return;
    }
    __shared__ float s_part[3][64][17];            // +1 pad: conflict-free
    const int tid = threadIdx.x;
    const int lpix = tid & 63;
    const int q = tid >> 6;                        // wave = t-quarter
    const int g = blockIdx.x * 64 + lpix;          // 0..16383
    const int b = g >> 12;
    const int n = g & (NPIX - 1);
    const int t0 = q * 48;
    const int cnt = (q == 3) ? 49 : 48;            // 48*3 + 49 = 193
    const float* sp = spike + ((size_t)(b * TDIM + START + t0)) * NPIX + n;
    const float4* w14 = (const float4*)w1 + (size_t)t0 * 4;

    float h[16];
#pragma unroll
    for (int k = 0; k < 16; ++k) h[k] = 0.f;

    int i = 0;
    for (; i + 8 <= cnt; i += 8) {
        float x[8];
#pragma unroll
        for (int u = 0; u < 8; ++u) x[u] = sp[(size_t)(i + u) * NPIX];
#pragma unroll
        for (int u = 0; u < 8; ++u) {
            const float4 wa = w14[(i + u) * 4 + 0];   // uniform -> s_load
            const float4 wb = w14[(i + u) * 4 + 1];
            const float4 wc = w14[(i + u) * 4 + 2];
            const float4 wd = w14[(i + u) * 4 + 3];
            h[0] = fmaf(x[u], wa.x, h[0]);  h[1] = fmaf(x[u], wa.y, h[1]);
            h[2] = fmaf(x[u], wa.z, h[2]);  h[3] = fmaf(x[u], wa.w, h[3]);
            h[4] = fmaf(x[u], wb.x, h[4]);  h[5] = fmaf(x[u], wb.y, h[5]);
            h[6] = fmaf(x[u], wb.z, h[6]);  h[7] = fmaf(x[u], wb.w, h[7]);
            h[8] = fmaf(x[u], wc.x, h[8]);  h[9] = fmaf(x[u], wc.y, h[9]);
            h[10] = fmaf(x[u], wc.z, h[10]); h[11] = fmaf(x[u], wc.w, h[11]);
            h[12] = fmaf(x[u], wd.x, h[12]); h[13] = fmaf(x[u], wd.y, h[13]);
            h[14] = fmaf(x[u], wd.z, h[14]); h[15] = fmaf(x[u], wd.w, h[15]);
        }
    }
    for (; i < cnt; ++i) {
        float x = sp[(size_t)i * NPIX];
        const float4 wa = w14[i * 4 + 0];
        const float4 wb = w14[i * 4 + 1];
        const float4 wc = w14[i * 4 + 2];
        const float4 wd = w14[i * 4 + 3];
        h[0] = fmaf(x, wa.x, h[0]);  h[1] = fmaf(x, wa.y, h[1]);
        h[2] = fmaf(x, wa.z, h[2]);  h[3] = fmaf(x, wa.w, h[3]);
        h[4] = fmaf(x, wb.x, h[4]);  h[5] = fmaf(x, wb.y, h[5]);
        h[6] = fmaf(x, wb.z, h[6]);  h[7] = fmaf(x, wb.w, h[7]);
        h[8] = fmaf(x, wc.x, h[8]);  h[9] = fmaf(x, wc.y, h[9]);
        h[10] = fmaf(x, wc.z, h[10]); h[11] = fmaf(x, wc.w, h[11]);
        h[12] = fmaf(x, wd.x, h[12]); h[13] = fmaf(x, wd.y, h[13]);
        h[14] = fmaf(x, wd.z, h[14]); h[15] = fmaf(x, wd.w, h[15]);
    }

    if (q) {
#pragma unroll
        for (int k = 0; k < 16; ++k) s_part[q - 1][lpix][k] = h[k];
    }
    __syncthreads();
    if (q == 0) {
#pragma unroll
        for (int k = 0; k < 16; ++k)
            h[k] += s_part[0][lpix][k] + s_part[1][lpix][k] + s_part[2][lpix][k];
#pragma unroll
        for (int k = 0; k < 16; ++k) {
            float z = h[k] + b1[k];
            h[k] = z / (1.f + expf(-z));           // silu
        }
        float f[8];
#pragma unroll
        for (int m = 0; m < 8; ++m) f[m] = b2[m];
#pragma unroll
        for (int k = 0; k < 16; ++k) {
#pragma unroll
            for (int m = 0; m < 8; ++m)
                f[m] = fmaf(h[k], w2[k * 8 + m], f[m]);
        }
#pragma unroll
        for (int m = 0; m < 8; ++m) f[m] = f[m] / (1.f + expf(-f[m]));  // silu
        float nrm = 0.f;
#pragma unroll
        for (int m = 0; m < 8; ++m) nrm = fmaf(f[m], f[m], nrm);
        nrm = fmaxf(sqrtf(nrm), 1e-6f);
#pragma unroll
        for (int m = 0; m < 8; ++m) f[m] = f[m] / nrm;

        float4* o4 = (float4*)(fn + (size_t)g * 8);
        o4[0] = make_float4(f[0], f[1], f[2], f[3]);
        o4[1] = make_float4(f[4], f[5], f[6], f[7]);
    }
    if (blockIdx.x == 0 && tid == 0) *flag = 0;    // convergence flag
}

// ---------------------------------------------------------------------------
// Kernel 2: adjacency bitmask + lab1 = M(identity) = min set-bit per row.
// Dot-product summation kept STRICTLY sequential e0..e7 (matches XLA).
// Blocks >= NC are zero-streamers.
// ---------------------------------------------------------------------------
__global__ __launch_bounds__(256) void adj_kernel(
    const float* __restrict__ fn, u64* __restrict__ adj, int* __restrict__ lab,
    vfloat4* __restrict__ zb, int zn, int nc)
{
    if (blockIdx.x >= nc) {                        // zero-only block
        zero_slice_block(zb, zn, blockIdx.x - nc, gridDim.x - nc);
        return;
    }
    __shared__ float s_fj[1024 * 8];               // 32 KiB
    const int b  = blockIdx.x >> 8;
    const int i0 = (blockIdx.x & 255) << 4;
    const int tid = threadIdx.x;
    const int wave = tid >> 6, lane = tid & 63;
    const float* fnb = fn + (size_t)b * NPIX * 8;

    float fi[4][8];                                // 4 rows per wave
#pragma unroll
    for (int r = 0; r < 4; ++r) {
        const float* src = fnb + (size_t)(i0 + wave * 4 + r) * 8;
#pragma unroll
        for (int e = 0; e < 8; ++e) fi[r][e] = src[e];
    }
    u64 saved[4] = {0, 0, 0, 0};                   // word 'lane' of each row

    for (int jc = 0; jc < 4; ++jc) {
        __syncthreads();
        const float4* src4 = (const float4*)(fnb + (size_t)jc * 1024 * 8);
        float4* dst4 = (float4*)s_fj;
#pragma unroll
        for (int p = 0; p < 8; ++p) dst4[p * 256 + tid] = src4[p * 256 + tid];
        __syncthreads();

        for (int ww = 0; ww < 16; ++ww) {
            const int jl = ww * 64 + lane;
            const float4* pj = (const float4*)(s_fj + jl * 8);
            float4 a = pj[0], c = pj[1];
            float fj[8] = {a.x, a.y, a.z, a.w, c.x, c.y, c.z, c.w};
            const int widx = jc * 16 + ww;
#pragma unroll
            for (int r = 0; r < 4; ++r) {
                float d = 0.f;
#pragma unroll
                for (int e = 0; e < 8; ++e) d = fmaf(fj[e], fi[r][e], d);
                u64 mask = __ballot(d >= THRESH);
                if (lane == widx) saved[r] = mask;
            }
        }
    }
    u64* adjbase = adj + ((size_t)b * NPIX + i0) * 64;
#pragma unroll
    for (int r = 0; r < 4; ++r) {
        adjbase[(size_t)(wave * 4 + r) * 64 + lane] = saved[r];
        // lab1[row] = min set bit index (diag guarantees nonempty)
        int cand = saved[r] ? (lane * 64 + __ffsll(saved[r]) - 1) : NPIX;
#pragma unroll
        for (int off = 32; off > 0; off >>= 1)
            cand = min(cand, __shfl_xor(cand, off));
        if (lane == 0) lab[(b << 12) + i0 + wave * 4 + r] = cand;
    }
}

// ---------------------------------------------------------------------------
// Kernel 3: one round = J^3 then masked min, jmp rotate-swizzled in LDS
// (conflict-free both sides). Blocks >= NC are zero-streamers (they zero
// regardless of the convergence flag; compute blocks early-exit as before).
// ---------------------------------------------------------------------------
__global__ __launch_bounds__(256) void min_kernel(
    const u64* __restrict__ adj, const int* __restrict__ src,
    int* __restrict__ dst, int* __restrict__ flag, int round,
    vfloat4* __restrict__ zb, int zn, int nc)
{
    if (blockIdx.x >= nc) {                        // zero-only block
        zero_slice_block(zb, zn, blockIdx.x - nc, gridDim.x - nc);
        return;
    }
    if (round > 0 && flag[0] < round) return;      // converged: labels final
    __shared__ int sA[NPIX];                       // 16 KiB
    __shared__ int sB[NPIX];                       // 16 KiB (J^2 / swizzled jmp)
    __shared__ int s_chg;
    const int tid = threadIdx.x;
    if (tid == 0) s_chg = 0;
    const int wave = tid >> 6, lane = tid & 63;
    const int row0 = blockIdx.x * 32 + wave * 8;   // 8 rows per wave
    const int base = (row0 >> 12) << 12;           // batch base

    const int4* g4 = (const int4*)(src + base);
    int4* s4 = (int4*)sA;
#pragma unroll
    for (int p = 0; p < 4; ++p) s4[p * 256 + tid] = g4[p * 256 + tid];
    __syncthreads();
    // J^1: sA -> sB ; J^2: sB -> sA (linear layouts)
#pragma unroll
    for (int p = 0; p < 16; ++p) {
        int j = p * 256 + tid;
        sB[j] = sA[min(sA[j], NPIX - 1)];
    }
    __syncthreads();
#pragma unroll
    for (int p = 0; p < 16; ++p) {
        int j = p * 256 + tid;
        sA[j] = sB[min(sB[j], NPIX - 1)];
    }
    __syncthreads();
    // J^3: sA -> sB, written in rotate-swizzled transposed layout
#pragma unroll
    for (int p = 0; p < 16; ++p) {
        int j = p * 256 + tid;
        int v = sA[min(sA[j], NPIX - 1)];
        int bj = j & 63;                           // = lane
        int lj = j >> 6;                           // uniform per (p,wave)
        sB[(bj << 6) + ((lj + bj) & 63)] = v;      // conflict-free write
    }
    __syncthreads();

    const u64* arow = adj + (size_t)row0 * 64;
    uint32 lo[8], hi[8];
#pragma unroll
    for (int q = 0; q < 8; ++q) {
        u64 w = arow[(size_t)q * 64 + lane];       // word 'lane' of row q
        lo[q] = (uint32)w; hi[q] = (uint32)(w >> 32);
    }

    int m[8];
#pragma unroll
    for (int q = 0; q < 8; ++q) m[q] = NPIX;       // reference uses N as +inf
#pragma unroll
    for (int b = 0; b < 32; ++b) {
        const int jv = sB[(b << 6) + ((lane + b) & 63)];
#pragma unroll
        for (int q = 0; q < 8; ++q)
            m[q] = min(m[q], (lo[q] & (1u << b)) ? jv : NPIX);
    }
#pragma unroll
    for (int b = 0; b < 32; ++b) {
        const int jv = sB[((b + 32) << 6) + ((lane + b + 32) & 63)];
#pragma unroll
        for (int q = 0; q < 8; ++q)
            m[q] = min(m[q], (hi[q] & (1u << b)) ? jv : NPIX);
    }
#pragma unroll
    for (int off = 32; off > 0; off >>= 1) {
#pragma unroll
        for (int q = 0; q < 8; ++q) m[q] = min(m[q], __shfl_xor(m[q], off));
    }

    if (lane == 0) {
        bool chg = false;
#pragma unroll
        for (int q = 0; q < 8; ++q) {
            dst[row0 + q] = m[q];
            chg |= (m[q] != src[row0 + q]);
        }
        if (chg) s_chg = 1;
    }
    __syncthreads();
    if (tid == 0 && s_chg) *flag = round + 1;      // plain store, same value
}

// ---------------------------------------------------------------------------
// Kernel 4 (fallback only): standalone zero of the whole output.
// ---------------------------------------------------------------------------
__global__ __launch_bounds__(256) void zero_kernel(vfloat4* __restrict__ out)
{
    size_t idx = (size_t)blockIdx.x * 256 + threadIdx.x;
    const size_t stride = (size_t)2048 * 256;
    const vfloat4 z = {0.f, 0.f, 0.f, 0.f};
#pragma unroll
    for (int k = 0; k < 32; ++k) {
        out[idx] = z;
        idx += stride;
    }
}

// ---------------------------------------------------------------------------
// Kernel 5: final jump + is_root + cumsum rank + SCATTER of ones into the
// zeroed output: out[b][rank[lab[i]]][i] = 1.0f. One block per batch.
// ---------------------------------------------------------------------------
__global__ __launch_bounds__(256) void comp_scatter_kernel(
    const int* __restrict__ labsrc, float* __restrict__ out)
{
    __shared__ int s_lab[NPIX];                    // 16 KiB
    __shared__ int s_rank[NPIX];                   // 16 KiB
    __shared__ int s_wsum[4];
    const int b = blockIdx.x, tid = threadIdx.x;
    const int* lb = labsrc + (b << 12);

    for (int i = tid; i < NPIX; i += 256) s_lab[i] = lb[i];
    __syncthreads();

    // final pointer-jump (identity at fixed point; kept for exactness)
    int regs[16];
#pragma unroll
    for (int k = 0; k < 16; ++k) {
        int i = k * 256 + tid;
        regs[k] = s_lab[min(s_lab[i], NPIX - 1)];
    }
    __syncthreads();
#pragma unroll
    for (int k = 0; k < 16; ++k) s_lab[k * 256 + tid] = regs[k];
    __syncthreads();

    // inclusive cumsum of is_root, 16 contiguous elems per thread
    int loc[16];
    int sum = 0;
#pragma unroll
    for (int k = 0; k < 16; ++k) {
        int i = tid * 16 + k;
        sum += (s_lab[i] == i) ? 1 : 0;
        loc[k] = sum;
    }
    const int lane = tid & 63, wave = tid >> 6;
    int v = sum;
    for (int off = 1; off < 64; off <<= 1) {
        int u = __shfl_up(v, off);
        if (lane >= off) v += u;
    }
    if (lane == 63) s_wsum[wave] = v;
    __syncthreads();
    int waveoff = 0;
    for (int ww = 0; ww < 4; ++ww)
        if (ww < wave) waveoff += s_wsum[ww];
    const int excl = waveoff + v - sum;
#pragma unroll
    for (int k = 0; k < 16; ++k) s_rank[tid * 16 + k] = excl + loc[k] - 1;
    __syncthreads();

    float* ob = out + ((size_t)b << 24);           // batch base (4096*4096)
#pragma unroll
    for (int k = 0; k < 16; ++k) {
        int i = k * 256 + tid;
        int r = s_rank[min(s_lab[i], NPIX - 1)];   // JAX clamp on rank[labels]
        ob[((size_t)r << 12) + i] = 1.0f;          // one-hot scatter
    }
}

// ---------------------------------------------------------------------------
extern "C" void kernel_launch(void* const* d_in, const int* in_sizes, int n_in,
                              void* d_out, int out_size, void* d_ws, size_t ws_size,
                              hipStream_t stream)
{
    const float* spike = (const float*)d_in[0];
    const float* w1 = (const float*)d_in[1];
    const float* b1 = (const float*)d_in[2];
    const float* w2 = (const float*)d_in[3];
    const float* b2 = (const float*)d_in[4];

    const size_t ADJ_B = (size_t)8 * 1024 * 1024;          // adj bitmask
    const size_t FN_B  = (size_t)BATCH * NPIX * 8 * 4;     // features, 512 KiB
    const size_t LAB_B = (size_t)BATCH * NPIX * 4;         // one label buf
    const bool use_ws = ws_size >= ADJ_B + FN_B + 2 * LAB_B + 64;

    u64*   adj;
    float* fn;
    int *labA, *labB, *flag;
    if (use_ws) {
        char* w = (char*)d_ws;
        adj  = (u64*)w;
        fn   = (float*)(w + ADJ_B);
        labA = (int*)(w + ADJ_B + FN_B);
        labB = labA + BATCH * NPIX;
        flag = labB + BATCH * NPIX;
    } else {                                        // fallback: R12 layout
        adj  = (u64*)d_out;
        fn   = (float*)((char*)d_out + ADJ_B);
        labA = (int*)d_ws;
        labB = labA + BATCH * NPIX;
        flag = labB + BATCH * NPIX;
    }

    vfloat4* out4 = (vfloat4*)d_out;
    const int MI = 1024 * 1024;
    // zero-slice plan (float4 units, total 16Mi = 268 MB), executed by
    // DEDICATED zero blocks co-resident with compute blocks (R16 champion):
    //   feat 4Mi | adj 4Mi | round0 4Mi | round1 4Mi, 256 zero blocks each
    const int Z = 4 * MI;
    vfloat4* zf = use_ws ? out4 : nullptr;
    vfloat4* za = use_ws ? out4 + (size_t)Z : nullptr;
    vfloat4* z0 = use_ws ? out4 + (size_t)2 * Z : nullptr;
    vfloat4* z1 = use_ws ? out4 + (size_t)3 * Z : nullptr;
    const int ZB = use_ws ? 256 : 0;               // zero blocks per kernel

    // grids: compute blocks + ZB zero blocks
    feat_kernel<<<BATCH * NPIX / 64 + ZB, 256, 0, stream>>>(
        spike, w1, b1, w2, b2, fn, flag, zf, use_ws ? Z : 0, BATCH * NPIX / 64);
    adj_kernel<<<BATCH * 256 + ZB, 256, 0, stream>>>(
        fn, adj, labA, za, use_ws ? Z : 0, BATCH * 256);

    int* bufs[2] = {labA, labB};
    vfloat4* zr[2] = {z0, z1};
    for (int r = 0; r < ROUNDS; ++r)
        min_kernel<<<BATCH * NPIX / 32 + ZB, 256, 0, stream>>>(
            adj, bufs[r & 1], bufs[(r + 1) & 1], flag, r,
            zr[r], use_ws ? Z : 0, BATCH * NPIX / 32);

    if (!use_ws)
        zero_kernel<<<2048, 256, 0, stream>>>(out4);

    // final labels = round1's output (bufs[0])
    comp_scatter_kernel<<<BATCH, 256, 0, stream>>>(bufs[0], (float*)d_out);
}